// Round 22
// baseline (133.104 us; speedup 1.0000x reference)
//
#include <hip/hip_runtime.h>
#include <hip/hip_bf16.h>

#define D_MODEL 96
#define D_INNER 192
#define BATCH 32
#define HH 56
#define WW 56
#define NPIX (BATCH*HH*WW)   // 100352
#define LN_EPS 1e-5f
#define K2_NWG 1568          // NPIX / 64 = 8 * 196 (bijective XCD swizzle)
#define K2_CPX 196

typedef unsigned short ushort_t;
typedef __attribute__((ext_vector_type(8))) short short8;   // 8 bf16 (4 VGPRs)
typedef __attribute__((ext_vector_type(4))) float f32x4;

// g_Wt: conv weights [tap][oc][ic] bf16 PLAIN layout (r2-verified) — read
// directly from L2 as register fragments. g_Wit: in_proj [oc][ic] bf16.
__device__ __align__(16) ushort_t g_Wt[9 * 96 * 192];
__device__ __align__(16) ushort_t g_Wit[192 * 96];

static __device__ __forceinline__ unsigned short f2bf(float f) {
    unsigned u = __float_as_uint(f);
    unsigned r = (u + 0x7fffu + ((u >> 16) & 1u)) >> 16;
    return (unsigned short)r;
}

// ---------------------------------------------------------------------------
// Kernel 0: weight prep. g_Wt plain [tap][oc][ic] (r2 layout, verified).
// ---------------------------------------------------------------------------
__global__ __launch_bounds__(256) void k0_wt(const float* __restrict__ Wc,
                                             const float* __restrict__ Wi) {
    const int o = blockIdx.x * 256 + threadIdx.x;
    if (o < 9 * 18432) {
        const int tap = o / 18432;
        const int rem = o - tap * 18432;
        const int oc = rem / 192;
        const int ic = rem - oc * 192;
        g_Wt[o] = f2bf(Wc[(tap * 192 + ic) * 96 + oc]);
    }
    if (o < 192 * 96) {
        const int oc = o / 96, ic = o - oc * 96;
        g_Wit[o] = f2bf(Wi[ic * 384 + oc]);
    }
}

// ---------------------------------------------------------------------------
// Kernel 1: LayerNorm + in_projection (byte-identical to r21, verified):
// X1 stores pre-swizzled per pixel (byte ^= ((pix&7)<<4)).
// ---------------------------------------------------------------------------
__global__ __launch_bounds__(256) void k1_ln_proj(
    const float* __restrict__ X, const float* __restrict__ ln_w,
    const float* __restrict__ ln_b, const float* __restrict__ b_in,
    ushort_t* __restrict__ X1)
{
    __shared__ ushort_t sH[64 * 104];
    __shared__ ushort_t sO[64 * 200];
    const int t = threadIdx.x;

    const int g = t >> 2, tig = t & 3;
    const int pix = blockIdx.x * 64 + g;
    const float* xp = X + (size_t)pix * 96 + tig * 24;
    float4 xq[6];
    float s = 0.f;
    #pragma unroll
    for (int c = 0; c < 6; ++c) {
        xq[c] = *(const float4*)(xp + c * 4);
        s += xq[c].x + xq[c].y + xq[c].z + xq[c].w;
    }
    s += __shfl_xor(s, 1, 4);
    s += __shfl_xor(s, 2, 4);
    const float mu = s * (1.f / 96.f);
    float v = 0.f;
    #pragma unroll
    for (int c = 0; c < 6; ++c) {
        const float d0 = xq[c].x - mu, d1 = xq[c].y - mu;
        const float d2 = xq[c].z - mu, d3 = xq[c].w - mu;
        v += d0 * d0 + d1 * d1 + d2 * d2 + d3 * d3;
    }
    v += __shfl_xor(v, 1, 4);
    v += __shfl_xor(v, 2, 4);
    const float rs = rsqrtf(v * (1.f / 96.f) + LN_EPS);
    #pragma unroll
    for (int c = 0; c < 6; ++c) {
        const float4 lw = *(const float4*)(ln_w + tig * 24 + c * 4);
        const float4 lb = *(const float4*)(ln_b + tig * 24 + c * 4);
        const unsigned p0 = (unsigned)f2bf((xq[c].x - mu) * rs * lw.x + lb.x)
                          | ((unsigned)f2bf((xq[c].y - mu) * rs * lw.y + lb.y) << 16);
        const unsigned p1 = (unsigned)f2bf((xq[c].z - mu) * rs * lw.z + lb.z)
                          | ((unsigned)f2bf((xq[c].w - mu) * rs * lw.w + lb.w) << 16);
        uint2 u; u.x = p0; u.y = p1;
        *(uint2*)&sH[g * 104 + tig * 24 + c * 4] = u;
    }
    __syncthreads();

    const int w = t >> 6, l = t & 63;
    const int lm = l & 15, lq = l >> 4;
    const ushort_t* hp = &sH[(w * 16 + lm) * 104 + lq * 8];

    f32x4 acc[12];
    const f32x4 zf = {0.f, 0.f, 0.f, 0.f};
    #pragma unroll
    for (int mt = 0; mt < 12; ++mt) acc[mt] = zf;

    #pragma unroll
    for (int kk = 0; kk < 3; ++kk) {
        const short8 hb = *(const short8*)(hp + kk * 32);
        #pragma unroll
        for (int mt = 0; mt < 12; ++mt) {
            const short8 wa = *(const short8*)(g_Wit + (mt * 16 + lm) * 96 + kk * 32 + lq * 8);
            acc[mt] = __builtin_amdgcn_mfma_f32_16x16x32_bf16(wa, hb, acc[mt], 0, 0, 0);
        }
    }

    #pragma unroll
    for (int mt = 0; mt < 12; ++mt) {
        const int oc0 = mt * 16 + lq * 4;
        const float4 bv = *(const float4*)(b_in + oc0);
        uint2 u;
        u.x = (unsigned)f2bf(acc[mt][0] + bv.x) | ((unsigned)f2bf(acc[mt][1] + bv.y) << 16);
        u.y = (unsigned)f2bf(acc[mt][2] + bv.z) | ((unsigned)f2bf(acc[mt][3] + bv.w) << 16);
        *(uint2*)&sO[(w * 16 + lm) * 200 + oc0] = u;
    }
    __syncthreads();

    const char* sOb = (const char*)sO + w * 16 * 400;
    char* gdst = (char*)X1 + (size_t)(blockIdx.x * 64 + w * 16) * 384;
    #pragma unroll
    for (int c = 0; c < 6; ++c) {
        const int gb = c * 1024 + l * 16;
        const int px = gb / 384, b = gb - px * 384;
        const uint4 val = *(const uint4*)(sOb + px * 400 + b);
        *(uint4*)(gdst + (gb ^ ((px & 7) << 4))) = val;
    }
}

// ---------------------------------------------------------------------------
// Kernel 2: 3x3 conv (192 -> 96) MFMA + bias + SiLU + residual.
// ROUND-22: r21's verified halo path (FETCH 42 MB, conflicts 150 K) with the
// weight LDS slab REMOVED. r21 was 1 wave/SIMD (75.3 KB LDS -> 2 blocks/CU)
// with 18 stageW barriers exposing every latency. Now: weights (331 KB,
// L2-hot) are prefetched into REGISTERS half-a-tap ahead (bL/bH, 9 short8
// each, static indexing) -> zero barriers and zero LDS in the main loop.
// LDS = halo only (38,400 B) -> 4 blocks/CU = 8 waves/CU (2/SIMD).
// ---------------------------------------------------------------------------
__global__ __launch_bounds__(128) void k2_conv_mfma(
    const ushort_t* __restrict__ X1, const float* __restrict__ conv_b,
    const float* __restrict__ X, float* __restrict__ OUT)
{
    __shared__ ushort_t sX[100 * 192];   // 38,400 B halo (pre-swizzled blocks)
    const int t = threadIdx.x;
    const int w = t >> 6, l = t & 63;
    const int lm = l & 15, lq = l >> 4;

    const int lb = ((int)blockIdx.x & 7) * K2_CPX + ((int)blockIdx.x >> 3);
    const int img = lb / 49, tile = lb - img * 49;
    const int ty = (tile / 7) * 8, tx = (tile % 7) * 8;
    const size_t imgbase = (size_t)img * 3136 * 192;

    // ---- stage halo: verbatim copies (swizzle travels with the data) ----
    for (int idx = t; idx < 2400; idx += 128) {       // 100 px * 24 uint4
        const int hp2 = idx / 24, q = idx - hp2 * 24;
        const int hr = hp2 / 10, hc = hp2 - hr * 10;
        const int gr = ty + hr - 1, gc = tx + hc - 1;
        uint4 val = make_uint4(0u, 0u, 0u, 0u);
        if (gr >= 0 && gr < HH && gc >= 0 && gc < WW)
            val = *(const uint4*)(X1 + imgbase + (size_t)(gr * WW + gc) * 192 + q * 8);
        *(uint4*)&sX[hp2 * 192 + q * 8] = val;
    }

    // ---- per-lane weight fragment base: row = w*48 + n*16 + lm ----
    const ushort_t* bbase = g_Wt + (size_t)(w * 48 + lm) * 192 + lq * 8;
    // loadB9(buf, tap, half): 9 short8 fragments (3 n-tiles x 3 kk)
    auto loadB9 = [&](short8 (&buf)[9], int tap, int half) {
        const ushort_t* p = bbase + tap * 18432 + half * 96;   // half*3*32
        #pragma unroll
        for (int n = 0; n < 3; ++n)
            #pragma unroll
            for (int k2 = 0; k2 < 3; ++k2)
                buf[n * 3 + k2] = *(const short8*)(p + n * 3072 + k2 * 32);
    };

    int pr[4], pc[4];
    #pragma unroll
    for (int i = 0; i < 4; ++i) {
        const int px = i * 16 + lm;
        pr[i] = px >> 3; pc[i] = px & 7;
    }

    f32x4 acc[4][3];
    const f32x4 zf = {0.f, 0.f, 0.f, 0.f};
    #pragma unroll
    for (int i = 0; i < 4; ++i)
        #pragma unroll
        for (int n = 0; n < 3; ++n) acc[i][n] = zf;

    short8 bL[9], bH[9];
    loadB9(bL, 0, 0);                    // prologue (one exposed L2 latency)
    __syncthreads();                     // halo ready

    #pragma unroll 1
    for (int tap = 0; tap < 9; ++tap) {
        const int ky = tap / 3, kx = tap - (tap / 3) * 3;
        int abyte[4], akey[4];
        #pragma unroll
        for (int i = 0; i < 4; ++i) {
            abyte[i] = ((pr[i] + ky) * 10 + pc[i] + kx) * 384;
            akey[i] = ((tx + pc[i] + kx - 1) & 7) << 4;   // zero blocks: any key ok
        }

        loadB9(bH, tap, 1);              // in flight under half-0 compute
        #pragma unroll
        for (int k2 = 0; k2 < 3; ++k2) {
            const int kk = k2;
            short8 a[4];
            #pragma unroll
            for (int i = 0; i < 4; ++i) {
                const int s = (kk * 64 + lq * 16) ^ akey[i];
                a[i] = *(const short8*)((const char*)sX + abyte[i] + s);
            }
            #pragma unroll
            for (int i = 0; i < 4; ++i)
                #pragma unroll
                for (int n = 0; n < 3; ++n)
                    acc[i][n] = __builtin_amdgcn_mfma_f32_16x16x32_bf16(
                        a[i], bL[n * 3 + k2], acc[i][n], 0, 0, 0);
        }

        if (tap < 8) loadB9(bL, tap + 1, 0);   // in flight under half-1 compute
        #pragma unroll
        for (int k2 = 0; k2 < 3; ++k2) {
            const int kk = 3 + k2;
            short8 a[4];
            #pragma unroll
            for (int i = 0; i < 4; ++i) {
                const int s = (kk * 64 + lq * 16) ^ akey[i];
                a[i] = *(const short8*)((const char*)sX + abyte[i] + s);
            }
            #pragma unroll
            for (int i = 0; i < 4; ++i)
                #pragma unroll
                for (int n = 0; n < 3; ++n)
                    acc[i][n] = __builtin_amdgcn_mfma_f32_16x16x32_bf16(
                        a[i], bH[n * 3 + k2], acc[i][n], 0, 0, 0);
        }
    }
    __syncthreads();                     // both waves done reading sX

    // ---- epilogue: silu via LDS transpose (sX dead), coalesced stores ----
    float* sY = (float*)sX;              // 64 px * 100 dw = 25,600 B
    float bvn[3];
    #pragma unroll
    for (int n = 0; n < 3; ++n) bvn[n] = conv_b[w * 48 + n * 16 + lm];

    #pragma unroll
    for (int i = 0; i < 4; ++i)
        #pragma unroll
        for (int n = 0; n < 3; ++n)
            #pragma unroll
            for (int r4 = 0; r4 < 4; ++r4) {
                const float y = acc[i][n][r4] + bvn[n];
                const float sig = 1.f / (1.f + __expf(-y));
                sY[(i * 16 + lq * 4 + r4) * 100 + w * 48 + n * 16 + lm] = y * sig;
            }
    __syncthreads();

    #pragma unroll
    for (int c = 0; c < 12; ++c) {
        const int d = c * 512 + t * 4;                 // < 6144
        const int px = d / 96, b = d - px * 96;
        const int grow = ty + (px >> 3), gcol = tx + (px & 7);
        const size_t gdw = ((size_t)img * 3136 + grow * 56 + gcol) * 96 + b;
        const f32x4 yv = *(const f32x4*)(sY + px * 100 + b);
        const float4 xv = *(const float4*)(X + gdw);
        float4 o;
        o.x = xv.x + yv[0]; o.y = xv.y + yv[1];
        o.z = xv.z + yv[2]; o.w = xv.w + yv[3];
        *(float4*)(OUT + gdw) = o;
    }
}

extern "C" void kernel_launch(void* const* d_in, const int* in_sizes, int n_in,
                              void* d_out, int out_size, void* d_ws, size_t ws_size,
                              hipStream_t stream) {
    (void)in_sizes; (void)n_in; (void)out_size; (void)ws_size;
    const float* X    = (const float*)d_in[0];
    const float* ln_w = (const float*)d_in[1];
    const float* ln_b = (const float*)d_in[2];
    const float* Wi   = (const float*)d_in[3];
    const float* b_in = (const float*)d_in[4];
    const float* Wc   = (const float*)d_in[5];
    const float* cb   = (const float*)d_in[6];
    float* OUT = (float*)d_out;
    ushort_t* X1 = (ushort_t*)d_ws;   // 100352*192 bf16 = 38.5 MB (pre-swizzled)

    k0_wt<<<(9 * 96 * 192 + 255) / 256, 256, 0, stream>>>(Wc, Wi);
    k1_ln_proj<<<NPIX / 64, 256, 0, stream>>>(X, ln_w, ln_b, b_in, X1);
    k2_conv_mfma<<<K2_NWG, 128, 0, stream>>>(X1, cb, X, OUT);
}